// Round 1
// baseline (355.787 us; speedup 1.0000x reference)
//
#include <hip/hip_runtime.h>
#include <hip/hip_bf16.h>

typedef __attribute__((ext_vector_type(8))) short short8;
typedef __attribute__((ext_vector_type(4))) float f32x4;

constexpr int Bc = 4;
constexpr int Lc = 2048;
constexpr int Sc = 2048;
constexpr int Hc = 16;
constexpr int Ec = 64;
constexpr int Dc = 64;
constexpr int QBLK = 64;
constexpr int KBLK = 64;

__device__ __forceinline__ unsigned short f2bf(float x) {
  union { float f; unsigned u; } un; un.f = x;
  unsigned r = un.u + 0x7fffu + ((un.u >> 16) & 1u);
  return (unsigned short)(r >> 16);
}

__global__ __launch_bounds__(256, 2)
void fattn_kernel(const float* __restrict__ Qg, const float* __restrict__ Kg,
                  const float* __restrict__ Vg, float* __restrict__ Og) {
  // K tile: rows s (64), 64 bf16 each, 16B-chunk XOR swizzled by (s&7)
  __shared__ unsigned short Kl[KBLK * 64];
  // V^T tile: rows d (64), cols s (64), swizzled by (d&7)
  __shared__ unsigned short Vt[Dc * KBLK];
  // per-wave P tile: rows q (16), cols s (64), swizzled by (q&7)
  __shared__ unsigned short Pl[4][16 * KBLK];

  const int tid  = (int)threadIdx.x;
  const int wave = tid >> 6;
  const int lane = tid & 63;
  const int ln   = lane & 15;
  const int lh   = lane >> 4;

  const int qtile = (int)gridDim.x - 1 - (int)blockIdx.x;  // heavy tiles first
  const int bh = (int)blockIdx.y;
  const int b  = bh >> 4;   // H = 16
  const int h  = bh & 15;
  const int qb = qtile * QBLK;

  // ---- Q fragments, pre-scaled by 1/sqrt(E) * log2(e) (log2-domain softmax) ----
  const float QSCALE = 0.125f * 1.44269504088896341f;
  short8 qf[2];
  {
    const int q = qb + wave * 16 + ln;
    const float* qp = Qg + (((size_t)(b * Lc + q)) * Hc + h) * Ec;
#pragma unroll
    for (int c = 0; c < 2; ++c) {
      const float4* p4 = (const float4*)(qp + c * 32 + lh * 8);
      float4 x = p4[0], y = p4[1];
      qf[c][0] = (short)f2bf(x.x * QSCALE);
      qf[c][1] = (short)f2bf(x.y * QSCALE);
      qf[c][2] = (short)f2bf(x.z * QSCALE);
      qf[c][3] = (short)f2bf(x.w * QSCALE);
      qf[c][4] = (short)f2bf(y.x * QSCALE);
      qf[c][5] = (short)f2bf(y.y * QSCALE);
      qf[c][6] = (short)f2bf(y.z * QSCALE);
      qf[c][7] = (short)f2bf(y.w * QSCALE);
    }
  }

  f32x4 acco[4];
#pragma unroll
  for (int dt = 0; dt < 4; ++dt) acco[dt] = (f32x4){0.f, 0.f, 0.f, 0.f};
  float mrow[4], lrow[4];
#pragma unroll
  for (int r = 0; r < 4; ++r) { mrow[r] = -1e30f; lrow[r] = 0.f; }

  const int nchunks = qtile + 1;
  for (int ch = 0; ch < nchunks; ++ch) {
    const bool diag = (ch == nchunks - 1);
    __syncthreads();  // all waves done reading previous K/V tiles
    // ---- stage K (rows) and V^T into LDS as bf16, swizzled ----
    {
      const int s  = tid >> 2;           // 0..63
      const int eq = (tid & 3) << 4;     // 0,16,32,48
      const int sg = ch * KBLK + s;
      const float4* kp4 = (const float4*)(Kg + (((size_t)(b * Sc + sg)) * Hc + h) * Ec + eq);
      const float4* vp4 = (const float4*)(Vg + (((size_t)(b * Sc + sg)) * Hc + h) * Dc + eq);
      float4 k0 = kp4[0], k1 = kp4[1], k2 = kp4[2], k3 = kp4[3];
      float4 v0 = vp4[0], v1 = vp4[1], v2 = vp4[2], v3 = vp4[3];
      short8 w0, w1;
      w0[0] = (short)f2bf(k0.x); w0[1] = (short)f2bf(k0.y);
      w0[2] = (short)f2bf(k0.z); w0[3] = (short)f2bf(k0.w);
      w0[4] = (short)f2bf(k1.x); w0[5] = (short)f2bf(k1.y);
      w0[6] = (short)f2bf(k1.z); w0[7] = (short)f2bf(k1.w);
      w1[0] = (short)f2bf(k2.x); w1[1] = (short)f2bf(k2.y);
      w1[2] = (short)f2bf(k2.z); w1[3] = (short)f2bf(k2.w);
      w1[4] = (short)f2bf(k3.x); w1[5] = (short)f2bf(k3.y);
      w1[6] = (short)f2bf(k3.z); w1[7] = (short)f2bf(k3.w);
      const int c0 = eq >> 3;  // 0,2,4,6
      *(short8*)&Kl[s * 64 + (((c0    ) ^ (s & 7)) << 3)] = w0;
      *(short8*)&Kl[s * 64 + (((c0 + 1) ^ (s & 7)) << 3)] = w1;
      float va[16] = {v0.x, v0.y, v0.z, v0.w, v1.x, v1.y, v1.z, v1.w,
                      v2.x, v2.y, v2.z, v2.w, v3.x, v3.y, v3.z, v3.w};
#pragma unroll
      for (int i = 0; i < 16; ++i) {
        const int d = eq + i;
        Vt[d * 64 + ((((s >> 3) ^ (d & 7))) << 3) + (s & 7)] = f2bf(va[i]);
      }
    }
    __syncthreads();

    // ---- S = Q K^T for this wave's 16 q-rows ----
    const int kmax = diag ? wave : 3;   // wave-uniform
    f32x4 accs[4];
#pragma unroll
    for (int ks = 0; ks < 4; ++ks) {
      if (ks <= kmax) {
        const int sr = ks * 16 + ln;
        f32x4 acc = (f32x4){0.f, 0.f, 0.f, 0.f};
#pragma unroll
        for (int c = 0; c < 2; ++c) {
          short8 kf = *(const short8*)&Kl[sr * 64 + ((((c << 2) | lh) ^ (sr & 7)) << 3)];
          acc = __builtin_amdgcn_mfma_f32_16x16x32_bf16(qf[c], kf, acc, 0, 0, 0);
        }
        if (diag && ks == kmax) {
          // diagonal subtile: mask s_loc > q_loc  (ln > lh*4 + r)
#pragma unroll
          for (int r = 0; r < 4; ++r)
            if (ln > lh * 4 + r) acc[r] = -1e30f;
        }
        accs[ks] = acc;
      } else {
        accs[ks] = (f32x4){-1e30f, -1e30f, -1e30f, -1e30f};
      }
    }

    // ---- online softmax (log2 domain); write P to per-wave LDS ----
#pragma unroll
    for (int r = 0; r < 4; ++r) {
      float mx = fmaxf(fmaxf(accs[0][r], accs[1][r]), fmaxf(accs[2][r], accs[3][r]));
      mx = fmaxf(mx, __shfl_xor(mx, 1, 16));
      mx = fmaxf(mx, __shfl_xor(mx, 2, 16));
      mx = fmaxf(mx, __shfl_xor(mx, 4, 16));
      mx = fmaxf(mx, __shfl_xor(mx, 8, 16));
      const float mnew  = fmaxf(mrow[r], mx);
      const float alpha = exp2f(mrow[r] - mnew);
      float psum = 0.f;
      const int q_loc = lh * 4 + r;
#pragma unroll
      for (int ks = 0; ks < 4; ++ks) {
        const float p = exp2f(accs[ks][r] - mnew);
        psum += p;
        const int s_loc = ks * 16 + ln;
        Pl[wave][q_loc * 64 + (((s_loc >> 3) ^ (q_loc & 7)) << 3) + (s_loc & 7)] = f2bf(p);
      }
      psum += __shfl_xor(psum, 1, 16);
      psum += __shfl_xor(psum, 2, 16);
      psum += __shfl_xor(psum, 4, 16);
      psum += __shfl_xor(psum, 8, 16);
      lrow[r] = lrow[r] * alpha + psum;
      mrow[r] = mnew;
#pragma unroll
      for (int dt = 0; dt < 4; ++dt) acco[dt][r] *= alpha;
    }

    // wave-internal LDS RAW: drain ds writes before fragment reads
    asm volatile("s_waitcnt lgkmcnt(0)" ::: "memory");

    // ---- O += P V ----
#pragma unroll
    for (int c = 0; c < 2; ++c) {
      short8 pf = *(const short8*)&Pl[wave][ln * 64 + ((((c << 2) | lh) ^ (ln & 7)) << 3)];
#pragma unroll
      for (int dt = 0; dt < 4; ++dt) {
        short8 vf = *(const short8*)&Vt[(dt * 16 + ln) * 64 + ((((c << 2) | lh) ^ (ln & 7)) << 3)];
        acco[dt] = __builtin_amdgcn_mfma_f32_16x16x32_bf16(pf, vf, acco[dt], 0, 0, 0);
      }
    }
  }

  // ---- epilogue: O / l ----
#pragma unroll
  for (int r = 0; r < 4; ++r) {
    const int q = qb + wave * 16 + lh * 4 + r;
    const float inv = 1.0f / lrow[r];
    float* op = Og + (((size_t)(b * Lc + q)) * Hc + h) * Dc;
#pragma unroll
    for (int dt = 0; dt < 4; ++dt)
      op[dt * 16 + ln] = acco[dt][r] * inv;
  }
}

extern "C" void kernel_launch(void* const* d_in, const int* in_sizes, int n_in,
                              void* d_out, int out_size, void* d_ws, size_t ws_size,
                              hipStream_t stream) {
  const float* Q = (const float*)d_in[0];
  const float* K = (const float*)d_in[1];
  const float* V = (const float*)d_in[2];
  float* O = (float*)d_out;
  dim3 grid(Lc / QBLK, Bc * Hc);
  fattn_kernel<<<grid, 256, 0, stream>>>(Q, K, V, O);
}

// Round 3
// 256.074 us; speedup vs baseline: 1.3894x; 1.3894x over previous
//
#include <hip/hip_runtime.h>
#include <hip/hip_bf16.h>

typedef __attribute__((ext_vector_type(8))) short short8;
typedef __attribute__((ext_vector_type(4))) short short4v;
typedef __attribute__((ext_vector_type(4))) float f32x4;

constexpr int Bc = 4;
constexpr int Lc = 2048;
constexpr int Sc = 2048;
constexpr int Hc = 16;
constexpr int Ec = 64;
constexpr int Dc = 64;
constexpr int QBLK = 64;
constexpr int KBLK = 64;

__device__ __forceinline__ unsigned short f2bf(float x) {
  union { float f; unsigned u; } un; un.f = x;
  unsigned r = un.u + 0x7fffu + ((un.u >> 16) & 1u);
  return (unsigned short)(r >> 16);
}

__device__ __forceinline__ short8 cvt8(float4 a, float4 b) {
  short8 w;
  w[0] = (short)f2bf(a.x); w[1] = (short)f2bf(a.y);
  w[2] = (short)f2bf(a.z); w[3] = (short)f2bf(a.w);
  w[4] = (short)f2bf(b.x); w[5] = (short)f2bf(b.y);
  w[6] = (short)f2bf(b.z); w[7] = (short)f2bf(b.w);
  return w;
}

struct KV { float4 k[4]; float4 v[4]; };

__global__ __launch_bounds__(256, 2)
void fattn_kernel(const float* __restrict__ Qg, const float* __restrict__ Kg,
                  const float* __restrict__ Vg, float* __restrict__ Og) {
  // K tile (double-buffered): rows s (64) x 64 bf16, 16B-chunk XOR swizzled by s&7
  __shared__ unsigned short Kl[2][KBLK * 64];
  // V tile (double-buffered): subtiled [s/4][d/16][4][16] for ds_read_b64_tr_b16
  __shared__ unsigned short Vl[2][KBLK * 64];
  // per-wave P tile: rows q (16) x 64, swizzled by q&7
  __shared__ unsigned short Pl[4][16 * 64];

  const int tid  = (int)threadIdx.x;
  const int wave = tid >> 6;
  const int lane = tid & 63;
  const int ln   = lane & 15;
  const int lh   = lane >> 4;

  const int qtile = (int)gridDim.x - 1 - (int)blockIdx.x;  // heavy tiles first
  const int bh = (int)blockIdx.y;
  const int b  = bh >> 4;   // H = 16
  const int h  = bh & 15;
  const int qb = qtile * QBLK;

  // ---- Q fragments, pre-scaled by 1/sqrt(E)*log2(e) (log2-domain softmax) ----
  const float QSCALE = 0.125f * 1.44269504088896341f;
  short8 qf[2];
  {
    const int q = qb + wave * 16 + ln;
    const float* qp = Qg + (((size_t)(b * Lc + q)) * Hc + h) * Ec;
#pragma unroll
    for (int c = 0; c < 2; ++c) {
      const float4* p4 = (const float4*)(qp + c * 32 + lh * 8);
      float4 x = p4[0], y = p4[1];
      short8 w;
      w[0] = (short)f2bf(x.x * QSCALE); w[1] = (short)f2bf(x.y * QSCALE);
      w[2] = (short)f2bf(x.z * QSCALE); w[3] = (short)f2bf(x.w * QSCALE);
      w[4] = (short)f2bf(y.x * QSCALE); w[5] = (short)f2bf(y.y * QSCALE);
      w[6] = (short)f2bf(y.z * QSCALE); w[7] = (short)f2bf(y.w * QSCALE);
      qf[c] = w;
    }
  }

  // staging geometry: each thread owns row s, 16 consecutive elements at e0
  const int s  = tid >> 2;
  const int e0 = (tid & 3) << 4;

  auto loadKV = [&](int ch) {
    KV r;
    const size_t row = (((size_t)(b * Sc + ch * KBLK + s)) * Hc + h);
    const float4* kp4 = (const float4*)(Kg + row * Ec + e0);
    const float4* vp4 = (const float4*)(Vg + row * Dc + e0);
#pragma unroll
    for (int i = 0; i < 4; ++i) { r.k[i] = kp4[i]; r.v[i] = vp4[i]; }
    return r;
  };

  auto writeKV = [&](const KV& r, int buf) {
    short8 w0 = cvt8(r.k[0], r.k[1]);
    short8 w1 = cvt8(r.k[2], r.k[3]);
    const int c0 = e0 >> 3;  // 0,2,4,6
    *(short8*)&Kl[buf][s * 64 + (((c0    ) ^ (s & 7)) << 3)] = w0;
    *(short8*)&Kl[buf][s * 64 + (((c0 + 1) ^ (s & 7)) << 3)] = w1;
    short8 wv0 = cvt8(r.v[0], r.v[1]);
    short8 wv1 = cvt8(r.v[2], r.v[3]);
    // subtiled: elem off = ((s>>2)*4 + (d>>4))*64 + (s&3)*16 + (d&15)
    const int vt = ((s >> 2) * 4 + (tid & 3)) * 64 + (s & 3) * 16;
    *(short8*)&Vl[buf][vt]     = wv0;
    *(short8*)&Vl[buf][vt + 8] = wv1;
  };

  f32x4 acco[4];
#pragma unroll
  for (int dt = 0; dt < 4; ++dt) acco[dt] = (f32x4){0.f, 0.f, 0.f, 0.f};
  float mrow[4], lrow[4];
#pragma unroll
  for (int r = 0; r < 4; ++r) { mrow[r] = -1e30f; lrow[r] = 0.f; }

  const int nchunks = qtile + 1;

  // prologue: stage chunk 0 into buf 0
  { KV r0 = loadKV(0); writeKV(r0, 0); }
  __syncthreads();

  int cur = 0;
  for (int ch = 0; ch < nchunks; ++ch) {
    const bool diag = (ch == nchunks - 1);
    const bool pref = (ch + 1 < nchunks);
    // ---- issue next-chunk global loads early (latency hidden under compute) ----
    KV nxt;
    if (pref) nxt = loadKV(ch + 1);

    // ---- S = Q K^T for this wave's 16 q-rows ----
    const int kmax = diag ? wave : 3;   // wave-uniform
    f32x4 accs[4];
#pragma unroll
    for (int ks = 0; ks < 4; ++ks) {
      if (ks <= kmax) {
        const int sr = ks * 16 + ln;
        f32x4 acc = (f32x4){0.f, 0.f, 0.f, 0.f};
#pragma unroll
        for (int c = 0; c < 2; ++c) {
          short8 kf = *(const short8*)&Kl[cur][sr * 64 + ((((c << 2) | lh) ^ (sr & 7)) << 3)];
          acc = __builtin_amdgcn_mfma_f32_16x16x32_bf16(qf[c], kf, acc, 0, 0, 0);
        }
        if (diag && ks == kmax) {
#pragma unroll
          for (int r = 0; r < 4; ++r)
            if (ln > lh * 4 + r) acc[r] = -1e30f;
        }
        accs[ks] = acc;
      } else {
        accs[ks] = (f32x4){-1e30f, -1e30f, -1e30f, -1e30f};
      }
    }

    // ---- online softmax (log2 domain); write P to per-wave LDS ----
#pragma unroll
    for (int r = 0; r < 4; ++r) {
      float mx = fmaxf(fmaxf(accs[0][r], accs[1][r]), fmaxf(accs[2][r], accs[3][r]));
      mx = fmaxf(mx, __shfl_xor(mx, 1, 16));
      mx = fmaxf(mx, __shfl_xor(mx, 2, 16));
      mx = fmaxf(mx, __shfl_xor(mx, 4, 16));
      mx = fmaxf(mx, __shfl_xor(mx, 8, 16));
      const float mnew  = fmaxf(mrow[r], mx);
      const float alpha = exp2f(mrow[r] - mnew);
      float psum = 0.f;
      const int q_loc = lh * 4 + r;
#pragma unroll
      for (int ks = 0; ks < 4; ++ks) {
        const float p = exp2f(accs[ks][r] - mnew);
        psum += p;
        const int s_loc = ks * 16 + ln;
        Pl[wave][q_loc * 64 + (((s_loc >> 3) ^ (q_loc & 7)) << 3) + (s_loc & 7)] = f2bf(p);
      }
      psum += __shfl_xor(psum, 1, 16);
      psum += __shfl_xor(psum, 2, 16);
      psum += __shfl_xor(psum, 4, 16);
      psum += __shfl_xor(psum, 8, 16);
      lrow[r] = lrow[r] * alpha + psum;
      mrow[r] = mnew;
#pragma unroll
      for (int dt = 0; dt < 4; ++dt) acco[dt][r] *= alpha;
    }

    // ---- O += P V  (V consumed via hardware transpose reads) ----
    // tr_b16 mapping (m156): base = (a & ~127) + 2*((a>>3)&15); elem j at +32j bytes.
    // addr bits [6:3] select the COLUMN of the 4x16 subtile -> column ln needs 8*ln.
    const unsigned vbase = (unsigned)(size_t)(&Vl[cur][0]);
#pragma unroll
    for (int c = 0; c < 2; ++c) {
      short8 pf = *(const short8*)&Pl[wave][ln * 64 + ((((c << 2) | lh) ^ (ln & 7)) << 3)];
      short4v lo[4], hi[4];
#pragma unroll
      for (int dt = 0; dt < 4; ++dt) {
        // subtile index = (c*8+lh*2)*4 + dt ; column = ln
        const unsigned a0 = vbase + 512u * (c * 8 + lh * 2) + 128u * dt + 8u * ln;
        asm volatile("ds_read_b64_tr_b16 %0, %1 offset:0"   : "=v"(lo[dt]) : "v"(a0));
        asm volatile("ds_read_b64_tr_b16 %0, %1 offset:512" : "=v"(hi[dt]) : "v"(a0));
      }
      asm volatile("s_waitcnt lgkmcnt(0)" ::: "memory");
      __builtin_amdgcn_sched_barrier(0);
#pragma unroll
      for (int dt = 0; dt < 4; ++dt) {
        short8 vf = __builtin_shufflevector(lo[dt], hi[dt], 0, 1, 2, 3, 4, 5, 6, 7);
        acco[dt] = __builtin_amdgcn_mfma_f32_16x16x32_bf16(pf, vf, acco[dt], 0, 0, 0);
      }
    }

    // ---- stage next chunk into the other buffer, single barrier ----
    if (pref) writeKV(nxt, cur ^ 1);
    __syncthreads();
    cur ^= 1;
  }

  // ---- epilogue: O / l ----
#pragma unroll
  for (int r = 0; r < 4; ++r) {
    const int q = qb + wave * 16 + lh * 4 + r;
    const float inv = 1.0f / lrow[r];
    float* op = Og + (((size_t)(b * Lc + q)) * Hc + h) * Dc;
#pragma unroll
    for (int dt = 0; dt < 4; ++dt)
      op[dt * 16 + ln] = acco[dt][r] * inv;
  }
}

extern "C" void kernel_launch(void* const* d_in, const int* in_sizes, int n_in,
                              void* d_out, int out_size, void* d_ws, size_t ws_size,
                              hipStream_t stream) {
  const float* Q = (const float*)d_in[0];
  const float* K = (const float*)d_in[1];
  const float* V = (const float*)d_in[2];
  float* O = (float*)d_out;
  dim3 grid(Lc / QBLK, Bc * Hc);
  fattn_kernel<<<grid, 256, 0, stream>>>(Q, K, V, O);
}

// Round 4
// 214.447 us; speedup vs baseline: 1.6591x; 1.1941x over previous
//
#include <hip/hip_runtime.h>
#include <hip/hip_bf16.h>

typedef __attribute__((ext_vector_type(8))) short short8;
typedef __attribute__((ext_vector_type(4))) short short4v;
typedef __attribute__((ext_vector_type(4))) float f32x4;

constexpr int Bc = 4;
constexpr int Lc = 2048;
constexpr int Sc = 2048;
constexpr int Hc = 16;
constexpr int Ec = 64;
constexpr int Dc = 64;
constexpr int QBLK = 64;
constexpr int KBLK = 64;

// f32 -> bf16 RNE via compiler (pairs into v_cvt_pk_bf16_f32 on gfx950)
__device__ __forceinline__ unsigned short b16(float x) {
  __bf16 h = (__bf16)x;
  return __builtin_bit_cast(unsigned short, h);
}
__device__ __forceinline__ unsigned pk2(float lo, float hi) {
  return (unsigned)b16(lo) | ((unsigned)b16(hi) << 16);
}

__device__ __forceinline__ short8 cvt8(float4 a, float4 b) {
  short8 w;
  w[0] = (short)b16(a.x); w[1] = (short)b16(a.y);
  w[2] = (short)b16(a.z); w[3] = (short)b16(a.w);
  w[4] = (short)b16(b.x); w[5] = (short)b16(b.y);
  w[6] = (short)b16(b.z); w[7] = (short)b16(b.w);
  return w;
}

struct KV { float4 k[4]; float4 v[4]; };

__global__ __launch_bounds__(256, 4)
void fattn_kernel(const float* __restrict__ Qg, const float* __restrict__ Kg,
                  const float* __restrict__ Vg, float* __restrict__ Og) {
  // K tile (double-buffered): rows s (64) x 64 bf16, 16B-chunk XOR swizzled by s&7
  __shared__ unsigned short Kl[2][KBLK * 64];
  // V tile (double-buffered): subtiled [s/4][d/16][4][16] for ds_read_b64_tr_b16
  __shared__ unsigned short Vl[2][KBLK * 64];
  // per-wave P^T tile: [s/4 subtiles (16)][4 s-rows][16 q-cols], 2KB/wave
  __shared__ __attribute__((aligned(16))) unsigned short Pt[4][1024];

  const int tid  = (int)threadIdx.x;
  const int wave = tid >> 6;
  const int lane = tid & 63;
  const int ln   = lane & 15;
  const int lh   = lane >> 4;

  const int qtile = (int)gridDim.x - 1 - (int)blockIdx.x;  // heavy tiles first
  const int bh = (int)blockIdx.y;
  const int b  = bh >> 4;   // H = 16
  const int h  = bh & 15;
  const int qb = qtile * QBLK;

  // ---- Q fragments, pre-scaled by 1/sqrt(E)*log2(e) (log2-domain softmax) ----
  const float QSCALE = 0.125f * 1.44269504088896341f;
  short8 qf[2];
  {
    const int q = qb + wave * 16 + ln;
    const float* qp = Qg + (((size_t)(b * Lc + q)) * Hc + h) * Ec;
#pragma unroll
    for (int c = 0; c < 2; ++c) {
      const float4* p4 = (const float4*)(qp + c * 32 + lh * 8);
      float4 x = p4[0], y = p4[1];
      x.x *= QSCALE; x.y *= QSCALE; x.z *= QSCALE; x.w *= QSCALE;
      y.x *= QSCALE; y.y *= QSCALE; y.z *= QSCALE; y.w *= QSCALE;
      qf[c] = cvt8(x, y);
    }
  }

  // ones B-fragment (bf16 1.0) for the row-sum MFMA
  short8 ones;
#pragma unroll
  for (int j = 0; j < 8; ++j) ones[j] = (short)0x3F80;

  // staging geometry: each thread owns row s, 16 consecutive elements at e0
  const int s  = tid >> 2;
  const int e0 = (tid & 3) << 4;

  auto loadKV = [&](int ch) {
    KV r;
    const size_t row = (((size_t)(b * Sc + ch * KBLK + s)) * Hc + h);
    const float4* kp4 = (const float4*)(Kg + row * Ec + e0);
    const float4* vp4 = (const float4*)(Vg + row * Dc + e0);
#pragma unroll
    for (int i = 0; i < 4; ++i) { r.k[i] = kp4[i]; r.v[i] = vp4[i]; }
    return r;
  };

  auto writeKV = [&](const KV& r, int buf) {
    short8 w0 = cvt8(r.k[0], r.k[1]);
    short8 w1 = cvt8(r.k[2], r.k[3]);
    const int c0 = e0 >> 3;  // 0,2,4,6
    *(short8*)&Kl[buf][s * 64 + (((c0    ) ^ (s & 7)) << 3)] = w0;
    *(short8*)&Kl[buf][s * 64 + (((c0 + 1) ^ (s & 7)) << 3)] = w1;
    short8 wv0 = cvt8(r.v[0], r.v[1]);
    short8 wv1 = cvt8(r.v[2], r.v[3]);
    // subtiled: elem off = ((s>>2)*4 + (d>>4))*64 + (s&3)*16 + (d&15)
    const int vt = ((s >> 2) * 4 + (tid & 3)) * 64 + (s & 3) * 16;
    *(short8*)&Vl[buf][vt]     = wv0;
    *(short8*)&Vl[buf][vt + 8] = wv1;
  };

  f32x4 acco[4];
#pragma unroll
  for (int dt = 0; dt < 4; ++dt) acco[dt] = (f32x4){0.f, 0.f, 0.f, 0.f};
  f32x4 accl = (f32x4){0.f, 0.f, 0.f, 0.f};   // softmax denominator per q-row
  float mrow[4];
#pragma unroll
  for (int r = 0; r < 4; ++r) mrow[r] = -1e30f;

  const int nchunks = qtile + 1;

  // prologue: stage chunk 0 into buf 0
  { KV r0 = loadKV(0); writeKV(r0, 0); }
  __syncthreads();

  int cur = 0;
  for (int ch = 0; ch < nchunks; ++ch) {
    const bool diag = (ch == nchunks - 1);
    const bool pref = (ch + 1 < nchunks);
    // ---- issue next-chunk global loads early (latency hidden under compute) ----
    KV nxt;
    if (pref) nxt = loadKV(ch + 1);

    // ---- S = Q K^T for this wave's 16 q-rows ----
    const int kmax = diag ? wave : 3;   // wave-uniform
    f32x4 accs[4];
#pragma unroll
    for (int ks = 0; ks < 4; ++ks) {
      if (ks <= kmax) {
        const int sr = ks * 16 + ln;
        f32x4 acc = (f32x4){0.f, 0.f, 0.f, 0.f};
#pragma unroll
        for (int c = 0; c < 2; ++c) {
          short8 kf = *(const short8*)&Kl[cur][sr * 64 + ((((c << 2) | lh) ^ (sr & 7)) << 3)];
          acc = __builtin_amdgcn_mfma_f32_16x16x32_bf16(qf[c], kf, acc, 0, 0, 0);
        }
        if (diag && ks == kmax) {
#pragma unroll
          for (int r = 0; r < 4; ++r)
            if (ln > lh * 4 + r) acc[r] = -1e30f;
        }
        accs[ks] = acc;
      } else {
        accs[ks] = (f32x4){-1e30f, -1e30f, -1e30f, -1e30f};
      }
    }

    // ---- online softmax (log2 domain) ----
    float pv[4][4];  // pv[ks][r]
#pragma unroll
    for (int r = 0; r < 4; ++r) {
      float mx = fmaxf(fmaxf(accs[0][r], accs[1][r]), fmaxf(accs[2][r], accs[3][r]));
      mx = fmaxf(mx, __shfl_xor(mx, 1, 16));
      mx = fmaxf(mx, __shfl_xor(mx, 2, 16));
      mx = fmaxf(mx, __shfl_xor(mx, 4, 16));
      mx = fmaxf(mx, __shfl_xor(mx, 8, 16));
      const float mnew  = fmaxf(mrow[r], mx);
      const float alpha = exp2f(mrow[r] - mnew);
      mrow[r] = mnew;
#pragma unroll
      for (int ks = 0; ks < 4; ++ks) pv[ks][r] = exp2f(accs[ks][r] - mnew);
      accl[r] *= alpha;
#pragma unroll
      for (int dt = 0; dt < 4; ++dt) acco[dt][r] *= alpha;
    }

    // ---- write P^T to per-wave LDS: row s=16ks+ln, cols q=4lh..4lh+3 (one b64) ----
    {
      char* pb = (char*)&Pt[wave][0];
#pragma unroll
      for (int ks = 0; ks < 4; ++ks) {
        uint2 w;
        w.x = pk2(pv[ks][0], pv[ks][1]);
        w.y = pk2(pv[ks][2], pv[ks][3]);
        *(uint2*)(pb + (((4 * ks + (ln >> 2)) << 7) | ((ln & 3) << 5) | (lh << 3))) = w;
      }
    }
    asm volatile("" ::: "memory");  // pin P stores before the asm reads (DS is in-order per wave)

    // ---- O += P V  (P and V consumed via hardware transpose reads) ----
    const unsigned vbase = (unsigned)(size_t)(&Vl[cur][0]);
    const unsigned pbase = (unsigned)(size_t)(&Pt[wave][0]);
#pragma unroll
    for (int c = 0; c < 2; ++c) {
      short4v plo, phi;
      const unsigned pa = pbase + ((2 * lh + 8 * c) << 7) + (ln << 3);
      asm volatile("ds_read_b64_tr_b16 %0, %1 offset:0"   : "=v"(plo) : "v"(pa));
      asm volatile("ds_read_b64_tr_b16 %0, %1 offset:128" : "=v"(phi) : "v"(pa));
      short4v lo[4], hi[4];
#pragma unroll
      for (int dt = 0; dt < 4; ++dt) {
        const unsigned a0 = vbase + 512u * (c * 8 + lh * 2) + 128u * dt + 8u * ln;
        asm volatile("ds_read_b64_tr_b16 %0, %1 offset:0"   : "=v"(lo[dt]) : "v"(a0));
        asm volatile("ds_read_b64_tr_b16 %0, %1 offset:512" : "=v"(hi[dt]) : "v"(a0));
      }
      asm volatile("s_waitcnt lgkmcnt(0)" ::: "memory");
      __builtin_amdgcn_sched_barrier(0);
      short8 pf = __builtin_shufflevector(plo, phi, 0, 1, 2, 3, 4, 5, 6, 7);
      accl = __builtin_amdgcn_mfma_f32_16x16x32_bf16(pf, ones, accl, 0, 0, 0);
#pragma unroll
      for (int dt = 0; dt < 4; ++dt) {
        short8 vf = __builtin_shufflevector(lo[dt], hi[dt], 0, 1, 2, 3, 4, 5, 6, 7);
        acco[dt] = __builtin_amdgcn_mfma_f32_16x16x32_bf16(pf, vf, acco[dt], 0, 0, 0);
      }
    }

    // ---- stage next chunk into the other buffer, single barrier ----
    if (pref) writeKV(nxt, cur ^ 1);
    __syncthreads();
    cur ^= 1;
  }

  // ---- epilogue: O / l  (accl row r = denominator for q-row, uniform across ln) ----
#pragma unroll
  for (int r = 0; r < 4; ++r) {
    const int q = qb + wave * 16 + lh * 4 + r;
    const float inv = 1.0f / accl[r];
    float* op = Og + (((size_t)(b * Lc + q)) * Hc + h) * Dc;
#pragma unroll
    for (int dt = 0; dt < 4; ++dt)
      op[dt * 16 + ln] = acco[dt][r] * inv;
  }
}

extern "C" void kernel_launch(void* const* d_in, const int* in_sizes, int n_in,
                              void* d_out, int out_size, void* d_ws, size_t ws_size,
                              hipStream_t stream) {
  const float* Q = (const float*)d_in[0];
  const float* K = (const float*)d_in[1];
  const float* V = (const float*)d_in[2];
  float* O = (float*)d_out;
  dim3 grid(Lc / QBLK, Bc * Hc);
  fattn_kernel<<<grid, 256, 0, stream>>>(Q, K, V, O);
}

// Round 5
// 187.134 us; speedup vs baseline: 1.9012x; 1.1460x over previous
//
#include <hip/hip_runtime.h>
#include <hip/hip_bf16.h>

typedef __attribute__((ext_vector_type(8))) short short8;
typedef __attribute__((ext_vector_type(4))) short short4v;
typedef __attribute__((ext_vector_type(16))) float f32x16;

constexpr int Bc = 4;
constexpr int Lc = 2048;
constexpr int Sc = 2048;
constexpr int Hc = 16;
constexpr int Ec = 64;
constexpr int Dc = 64;
constexpr int QBLK = 128;   // 4 waves x 32 q-rows
constexpr int KBLK = 64;

__device__ __forceinline__ unsigned short b16(float x) {
  __bf16 h = (__bf16)x;
  return __builtin_bit_cast(unsigned short, h);
}
__device__ __forceinline__ unsigned pk2(float lo, float hi) {
  return (unsigned)b16(lo) | ((unsigned)b16(hi) << 16);
}
__device__ __forceinline__ short8 cvt8(float4 a, float4 b) {
  short8 w;
  w[0] = (short)b16(a.x); w[1] = (short)b16(a.y);
  w[2] = (short)b16(a.z); w[3] = (short)b16(a.w);
  w[4] = (short)b16(b.x); w[5] = (short)b16(b.y);
  w[6] = (short)b16(b.z); w[7] = (short)b16(b.w);
  return w;
}
__device__ __forceinline__ short8 mk8(unsigned d0, unsigned d1, unsigned d2, unsigned d3) {
  union { unsigned u[4]; short8 s; } t;
  t.u[0] = d0; t.u[1] = d1; t.u[2] = d2; t.u[3] = d3;
  return t.s;
}

struct KV { float4 k[4]; float4 v[4]; };

__global__ __launch_bounds__(256, 2)
void fattn_kernel(const float* __restrict__ Qg, const float* __restrict__ Kg,
                  const float* __restrict__ Vg, float* __restrict__ Og) {
  // K tile (dbuf): rows s(64) x 64 bf16, 16B-chunk XOR swizzle by s&7
  __shared__ unsigned short Kl[2][KBLK * 64];
  // V tile (dbuf): subtiled [s/4][d/16][4][16] for ds_read_b64_tr_b16
  __shared__ unsigned short Vl[2][KBLK * 64];

  const int tid  = (int)threadIdx.x;
  const int wave = tid >> 6;
  const int lane = tid & 63;
  const int q32  = lane & 31;   // q column / d column / A-B row index
  const int hi   = lane >> 5;

  const int qtile = (int)gridDim.x - 1 - (int)blockIdx.x;  // heavy tiles first
  const int bh = (int)blockIdx.y;
  const int b  = bh >> 4;
  const int h  = bh & 15;
  const int qb = qtile * QBLK;
  const int q0w = qb + wave * 32;   // this wave's first q row

  // ---- Q fragments (B-operand): lane holds Q row q32, k-elems 16c+8hi+j ----
  const float QSCALE = 0.125f * 1.44269504088896341f;  // 1/sqrt(64) * log2(e)
  short8 qf[4];
  {
    const float* qp = Qg + (((size_t)(b * Lc + q0w + q32)) * Hc + h) * Ec;
#pragma unroll
    for (int c = 0; c < 4; ++c) {
      const float4* p4 = (const float4*)(qp + c * 16 + hi * 8);
      float4 x = p4[0], y = p4[1];
      x.x *= QSCALE; x.y *= QSCALE; x.z *= QSCALE; x.w *= QSCALE;
      y.x *= QSCALE; y.y *= QSCALE; y.z *= QSCALE; y.w *= QSCALE;
      qf[c] = cvt8(x, y);
    }
  }

  short8 ones;
#pragma unroll
  for (int j = 0; j < 8; ++j) ones[j] = (short)0x3F80;

  // staging geometry: thread owns row s, 16 consecutive elems at e0
  const int s  = tid >> 2;
  const int e0 = (tid & 3) << 4;

  auto loadKV = [&](int ch) {
    KV r;
    const size_t row = (((size_t)(b * Sc + ch * KBLK + s)) * Hc + h);
    const float4* kp4 = (const float4*)(Kg + row * Ec + e0);
    const float4* vp4 = (const float4*)(Vg + row * Dc + e0);
#pragma unroll
    for (int i = 0; i < 4; ++i) { r.k[i] = kp4[i]; r.v[i] = vp4[i]; }
    return r;
  };

  auto writeKV = [&](const KV& r, int buf) {
    short8 w0 = cvt8(r.k[0], r.k[1]);
    short8 w1 = cvt8(r.k[2], r.k[3]);
    const int c0 = e0 >> 3;
    *(short8*)&Kl[buf][s * 64 + (((c0    ) ^ (s & 7)) << 3)] = w0;
    *(short8*)&Kl[buf][s * 64 + (((c0 + 1) ^ (s & 7)) << 3)] = w1;
    short8 wv0 = cvt8(r.v[0], r.v[1]);
    short8 wv1 = cvt8(r.v[2], r.v[3]);
    const int vt = ((s >> 2) * 4 + (tid & 3)) * 64 + (s & 3) * 16;
    *(short8*)&Vl[buf][vt]     = wv0;
    *(short8*)&Vl[buf][vt + 8] = wv1;
  };

  f32x16 acco0 = (f32x16)(0.f), acco1 = (f32x16)(0.f), accl = (f32x16)(0.f);
  float m_run = -1e30f;   // running max, column layout (per q=q32, both halves)

  const int nch = 2 * qtile + 2;

  { KV r0 = loadKV(0); writeKV(r0, 0); }
  __syncthreads();

  int cur = 0;
  for (int ch = 0; ch < nch; ++ch) {
    const bool pref = (ch + 1 < nch);
    KV nxt;
    if (pref) nxt = loadKV(ch + 1);

    const int s0 = ch * 64;
    const bool act0  = (s0      <= q0w);
    const bool act1  = (s0 + 32 <= q0w);
    const bool diag0 = (s0      == q0w);
    const bool diag1 = (s0 + 32 == q0w);

    if (act0) {
      // ---- S^T = K Q^T  (swapped: rows=s, cols=q) ----
      auto qk = [&](int sb) {
        f32x16 acc = (f32x16)(0.f);
        const int sr = sb * 32 + q32;
        const int rb = sr * 64;
        const int sw = sr & 7;
#pragma unroll
        for (int c = 0; c < 4; ++c) {
          short8 kf = *(const short8*)&Kl[cur][rb + (((2 * c + hi) ^ sw) << 3)];
          acc = __builtin_amdgcn_mfma_f32_32x32x16_bf16(kf, qf[c], acc, 0, 0, 0);
        }
        return acc;
      };
      f32x16 S0 = qk(0);
      f32x16 S1;
      if (act1) S1 = qk(1);

      // diagonal mask: s_loc = (r&3)+8*(r>>2)+4*hi  >  q_loc = q32
      const int tq = q32 - 4 * hi;
      if (diag0) {
#pragma unroll
        for (int r = 0; r < 16; ++r)
          if (((r & 3) + 8 * (r >> 2)) > tq) S0[r] = -1e30f;
      }
      if (act1 && diag1) {
#pragma unroll
        for (int r = 0; r < 16; ++r)
          if (((r & 3) + 8 * (r >> 2)) > tq) S1[r] = -1e30f;
      }

      // ---- chunk max (in-lane + cross-half via permlane32_swap) ----
      float pmax = S0[0];
#pragma unroll
      for (int r = 1; r < 16; ++r) pmax = fmaxf(pmax, S0[r]);
      if (act1) {
#pragma unroll
        for (int r = 0; r < 16; ++r) pmax = fmaxf(pmax, S1[r]);
      }
      {
        unsigned px = __builtin_bit_cast(unsigned, pmax);
        auto sw = __builtin_amdgcn_permlane32_swap(px, px, false, false);
        pmax = fmaxf(__builtin_bit_cast(float, (unsigned)sw[0]),
                     __builtin_bit_cast(float, (unsigned)sw[1]));
      }

      // ---- defer-max: rescale only when max grew past THR (T13) ----
      if (!__all(pmax - m_run <= 8.0f)) {
        const float mnew  = fmaxf(m_run, pmax);
        const float alpha = exp2f(m_run - mnew);
        m_run = mnew;
        const int hib = hi << 4;
        const int av  = __builtin_bit_cast(int, alpha);
#pragma unroll
        for (int r = 0; r < 16; ++r) {
          const int addr = hib + 4 * ((r & 3) + 8 * (r >> 2));
          float ar = __builtin_bit_cast(float, __builtin_amdgcn_ds_bpermute(addr, av));
          acco0[r] *= ar; acco1[r] *= ar; accl[r] *= ar;
        }
      }

      // ---- P = exp2(S - m) (bounded by 2^8) ----
#pragma unroll
      for (int r = 0; r < 16; ++r) S0[r] = exp2f(S0[r] - m_run);
      if (act1) {
#pragma unroll
        for (int r = 0; r < 16; ++r) S1[r] = exp2f(S1[r] - m_run);
      }

      // ---- issue V transpose-reads early (latency hidden under pa build) ----
      const unsigned vbase = (unsigned)(size_t)(&Vl[cur][0]);
      const unsigned vcol  = ((unsigned)(q32 & 15) << 3);
      const unsigned vrow  = (unsigned)(2 * (q32 >> 4));   // 2*dt + (q32>>4) term, dt part added below
      short4v vlo[2][4], vhi[2][4];
      const int ksmax = act1 ? 4 : 2;
#pragma unroll
      for (int ks = 0; ks < 4; ++ks) {
        if (ks < 2 || act1) {
#pragma unroll
          for (int dt = 0; dt < 2; ++dt) {
            const unsigned a0 = vbase +
              ((((unsigned)(4 * ks + 2 * hi) * 4u) + 2u * dt + (unsigned)(q32 >> 4)) << 7) + vcol;
            asm volatile("ds_read_b64_tr_b16 %0, %1 offset:0"   : "=v"(vlo[dt][ks]) : "v"(a0));
            asm volatile("ds_read_b64_tr_b16 %0, %1 offset:512" : "=v"(vhi[dt][ks]) : "v"(a0));
          }
        }
      }

      // ---- build PV A-fragments: 16 cvt_pk + 8 permlane32_swap (T12) ----
      auto mkpa = [&](const f32x16& P, int a, int bidx) {
        unsigned A0 = pk2(P[4 * a + 0],    P[4 * a + 1]);
        unsigned A1 = pk2(P[4 * a + 2],    P[4 * a + 3]);
        unsigned B0 = pk2(P[4 * bidx + 0], P[4 * bidx + 1]);
        unsigned B1 = pk2(P[4 * bidx + 2], P[4 * bidx + 3]);
        auto r0 = __builtin_amdgcn_permlane32_swap(A0, B0, false, false);
        auto r1 = __builtin_amdgcn_permlane32_swap(A1, B1, false, false);
        return mk8((unsigned)r0[0], (unsigned)r1[0], (unsigned)r0[1], (unsigned)r1[1]);
      };
      short8 pa0 = mkpa(S0, 0, 1);
      short8 pa1 = mkpa(S0, 2, 3);
      short8 pa2, pa3;
      if (act1) { pa2 = mkpa(S1, 0, 1); pa3 = mkpa(S1, 2, 3); }

      asm volatile("s_waitcnt lgkmcnt(0)" ::: "memory");
      __builtin_amdgcn_sched_barrier(0);

      // ---- denominator via ones-MFMA (row layout matches acco) ----
      accl = __builtin_amdgcn_mfma_f32_32x32x16_bf16(pa0, ones, accl, 0, 0, 0);
      accl = __builtin_amdgcn_mfma_f32_32x32x16_bf16(pa1, ones, accl, 0, 0, 0);
      if (act1) {
        accl = __builtin_amdgcn_mfma_f32_32x32x16_bf16(pa2, ones, accl, 0, 0, 0);
        accl = __builtin_amdgcn_mfma_f32_32x32x16_bf16(pa3, ones, accl, 0, 0, 0);
      }

      // ---- O += P V ----
#pragma unroll
      for (int dt = 0; dt < 2; ++dt) {
        f32x16& ac = dt ? acco1 : acco0;
        short8 vf0 = __builtin_shufflevector(vlo[dt][0], vhi[dt][0], 0,1,2,3,4,5,6,7);
        short8 vf1 = __builtin_shufflevector(vlo[dt][1], vhi[dt][1], 0,1,2,3,4,5,6,7);
        ac = __builtin_amdgcn_mfma_f32_32x32x16_bf16(pa0, vf0, ac, 0, 0, 0);
        ac = __builtin_amdgcn_mfma_f32_32x32x16_bf16(pa1, vf1, ac, 0, 0, 0);
        if (act1) {
          short8 vf2 = __builtin_shufflevector(vlo[dt][2], vhi[dt][2], 0,1,2,3,4,5,6,7);
          short8 vf3 = __builtin_shufflevector(vlo[dt][3], vhi[dt][3], 0,1,2,3,4,5,6,7);
          ac = __builtin_amdgcn_mfma_f32_32x32x16_bf16(pa2, vf2, ac, 0, 0, 0);
          ac = __builtin_amdgcn_mfma_f32_32x32x16_bf16(pa3, vf3, ac, 0, 0, 0);
        }
      }
    }

    if (pref) writeKV(nxt, cur ^ 1);
    __syncthreads();
    cur ^= 1;
  }

  // ---- epilogue: O = acco / accl  (same row layout, no transport) ----
#pragma unroll
  for (int r = 0; r < 16; ++r) {
    const int q_loc = (r & 3) + 8 * (r >> 2) + 4 * hi;
    const int q = q0w + q_loc;
    const float inv = 1.0f / accl[r];
    float* op = Og + (((size_t)(b * Lc + q)) * Hc + h) * Dc + q32;
    op[0]  = acco0[r] * inv;
    op[32] = acco1[r] * inv;
  }
}

extern "C" void kernel_launch(void* const* d_in, const int* in_sizes, int n_in,
                              void* d_out, int out_size, void* d_ws, size_t ws_size,
                              hipStream_t stream) {
  const float* Q = (const float*)d_in[0];
  const float* K = (const float*)d_in[1];
  const float* V = (const float*)d_in[2];
  float* O = (float*)d_out;
  dim3 grid(Lc / QBLK, Bc * Hc);
  fattn_kernel<<<grid, 256, 0, stream>>>(Q, K, V, O);
}